// Round 1
// baseline (466.777 us; speedup 1.0000x reference)
//
#include <hip/hip_runtime.h>

typedef short s8v  __attribute__((ext_vector_type(8)));
typedef float f4v  __attribute__((ext_vector_type(4)));
typedef int   v4i  __attribute__((ext_vector_type(4)));
typedef float v4f  __attribute__((ext_vector_type(4)));
typedef int   v2i  __attribute__((ext_vector_type(2)));

#define NNODES 8192
#define FDIM   256
#define NJC    8          // j-chunks (split-K factor)  (R10: 4->8 for 4 blocks/CU)
#define JLEN   1024       // columns-j per chunk
#define TROWS  64         // rows per block (B-frag reg reuse x4)
#define KSTEP  32         // k per step = one PB k-tile
#define NSTEP  32         // JLEN / KSTEP

__device__ __forceinline__ float bf2f(unsigned short u) {
    unsigned int x = ((unsigned int)u) << 16;
    return __builtin_bit_cast(float, x);
}
__device__ __forceinline__ unsigned short f2bf(float f) {
    unsigned int x = __builtin_bit_cast(unsigned int, f);
    x += 0x7fffu + ((x >> 16) & 1u);
    return (unsigned short)(x >> 16);
}
// RTNE pack of 2 f32 -> 1 dword of 2 bf16 (single VALU op; replaces ~8-op
// hand-rolled pair of f2bf + pack)
__device__ __forceinline__ int cvt_pk(float lo, float hi) {
    int r;
    asm("v_cvt_pk_bf16_f32 %0, %1, %2" : "=v"(r) : "v"(lo), "v"(hi));
    return r;
}

// ---------------- Kernel 0: WT[n][k] = bf16(W[k][n]) ----------------
__global__ __launch_bounds__(256) void wt_kernel(const float* __restrict__ W,
                                                 unsigned short* __restrict__ WT) {
    int idx = blockIdx.x * 256 + threadIdx.x;
    int r = idx >> 8, c = idx & 255;
    WT[c * 256 + r] = f2bf(W[r * 256 + c]);
}

// ---------------- Kernel 0b: v1 = W @ a[:256], v2 = W @ a[256:] ----------------
__global__ __launch_bounds__(256) void wv_kernel(const float* __restrict__ W,
                                                 const float* __restrict__ a,
                                                 float* __restrict__ v1, float* __restrict__ v2) {
    __shared__ float r1[256], r2[256];
    int b = blockIdx.x, n = threadIdx.x;
    float w = W[(size_t)b * FDIM + n];
    r1[n] = w * a[n];
    r2[n] = w * a[FDIM + n];
    __syncthreads();
    for (int off = 128; off > 0; off >>= 1) {
        if (n < off) { r1[n] += r1[n + off]; r2[n] += r2[n + off]; }
        __syncthreads();
    }
    if (n == 0) { v1[b] = r1[0]; v2[b] = r2[0]; }
}

// ---------------- Kernel 1: PB = tiled bf16 Wh; s1/s2 = h@v (fp32) ----------------
// PB: for k-block kb (32 Wh-rows) and n-block t (16 cols), 1 KiB tile:
//   PB[(kb*16+t)*512 + l15*32 + q*8 + jj] = Wh[kb*32 + q*8 + jj][t*16 + l15]
// -> one wave's MFMA B-frag = one contiguous aligned 1 KiB = 16 lines (min).
__global__ __launch_bounds__(256) void wh_kernel(
    const float* __restrict__ h, const unsigned short* __restrict__ WT,
    const float* __restrict__ v1, const float* __restrict__ v2,
    unsigned short* __restrict__ PB,
    float* __restrict__ s1, float* __restrict__ s2)
{
    __shared__ float v1_lds[FDIM], v2_lds[FDIM];
    int tid = threadIdx.x;
    v1_lds[tid] = v1[tid];
    v2_lds[tid] = v2[tid];
    __syncthreads();

    int w = tid >> 6, lane = tid & 63, q = lane >> 4, l15 = lane & 15;
    int i_base = blockIdx.x * 64 + w * 16;

    f4v acc[16] = {};
    float s1p = 0.f, s2p = 0.f;

    for (int k0 = 0; k0 < 256; k0 += 32) {
        const float* hp = h + (size_t)(i_base + l15) * FDIM + k0 + q * 8;
        f4v h0 = *(const f4v*)hp;
        f4v h1 = *(const f4v*)(hp + 4);
        union { v4i u; s8v s; } af;
        af.u[0] = cvt_pk(h0[0], h0[1]);
        af.u[1] = cvt_pk(h0[2], h0[3]);
        af.u[2] = cvt_pk(h1[0], h1[1]);
        af.u[3] = cvt_pk(h1[2], h1[3]);
#pragma unroll
        for (int j = 0; j < 4; ++j) {
            s1p += h0[j] * v1_lds[k0 + q * 8 + j] + h1[j] * v1_lds[k0 + q * 8 + 4 + j];
            s2p += h0[j] * v2_lds[k0 + q * 8 + j] + h1[j] * v2_lds[k0 + q * 8 + 4 + j];
        }
#pragma unroll
        for (int t = 0; t < 16; ++t) {
            s8v bf = *(const s8v*)(WT + (size_t)(t * 16 + l15) * FDIM + k0 + q * 8);
            acc[t] = __builtin_amdgcn_mfma_f32_16x16x32_bf16(af.s, bf, acc[t], 0, 0, 0);
        }
    }

    s1p += __shfl_xor(s1p, 16, 64);
    s1p += __shfl_xor(s1p, 32, 64);
    s2p += __shfl_xor(s2p, 16, 64);
    s2p += __shfl_xor(s2p, 32, 64);
    if (lane < 16) {
        s1[i_base + lane] = s1p;
        s2[i_base + lane] = s2p;
    }

    // packed epilogue: r=0..3 are 4 consecutive shorts at fixed (t,q)
#pragma unroll
    for (int t = 0; t < 16; ++t) {
        int i0 = i_base + q * 4;
        size_t a16 = (size_t)((i0 >> 5) * 16 + t) * 512
                   + l15 * 32 + ((i0 >> 3) & 3) * 8 + (i0 & 7);
        v2i pk;
        pk[0] = cvt_pk(acc[t][0], acc[t][1]);
        pk[1] = cvt_pk(acc[t][2], acc[t][3]);
        *(v2i*)(PB + a16) = pk;
    }
}

// ---------------- Kernel 2: split-K partial attention ----------------
// grid 1024 = 128 row-tiles x 8 j-chunks, 256 threads. Block: 64 rows x 256
// cols, 32 steps of k=32. jc = blockIdx&7 -> jc pinned to XCD: each XCD's L2
// only holds ONE 0.5 MiB PB slice. 4 blocks/CU (16 waves) for latency hiding
// (R10: grid 512 @ 2 blocks/CU was the occupancy limiter).
__global__ __launch_bounds__(256, 4) void attn_partial(
    const int* __restrict__ adj, const unsigned short* __restrict__ PB,
    const float* __restrict__ s1, const float* __restrict__ s2,
    float* __restrict__ Npart, float* __restrict__ dpart)
{
    __shared__ float s2_lds[JLEN];                      // 4 KB
    __shared__ unsigned short P_lds[2][TROWS * KSTEP];  // 2 x 4 KB
    __shared__ float dsum_lds[TROWS][4];

    int tid = threadIdx.x;
    int jc = blockIdx.x & 7, rt = blockIdx.x >> 3;
    int j0 = jc * JLEN;

    for (int i = tid; i < JLEN / 4; i += 256)
        ((v4f*)s2_lds)[i] = ((const v4f*)(s2 + j0))[i];

    // P-generator role: (row m 0..63, k-slice idx 0..3), 8 j's per thread/step
    int m = tid >> 2, idx = tid & 3;
    int row_g = rt * TROWS + m;
    float s1v = s1[row_g];
    const int* arow = adj + (size_t)row_g * NNODES + j0 + idx * 8;
    // write slot = idx*64+m, elem addr ^ idx*16 (matches reader swizzle)
    int woff = ((idx * 64 + m) * 8) ^ (idx * 16);

    // MFMA role: wave g -> cols g*64 + t*16 + l15; rowhalves rh=0..3 in-register
    int g = tid >> 6, lane = tid & 63, q = lane >> 4, l15 = lane & 15;
    const unsigned short* pbb = PB + (size_t)(jc * 32) * 16 * 512 + l15 * 32 + q * 8;

    f4v acc[4][4] = {};
    float dsum = 0.0f;

    __syncthreads();  // s2 staged

    // prologue: adj(step0) -> P0; adj(step1) parked in cur
    v4i a0 = __builtin_nontemporal_load((const v4i*)(arow));
    v4i a1 = __builtin_nontemporal_load((const v4i*)(arow + 4));
    v4i cur0 = __builtin_nontemporal_load((const v4i*)(arow + KSTEP));
    v4i cur1 = __builtin_nontemporal_load((const v4i*)(arow + KSTEP + 4));
    {
        int kb = idx * 8;
        v4f sA = *(const v4f*)&s2_lds[kb];
        v4f sB = *(const v4f*)&s2_lds[kb + 4];
        float pa[4], pb_[4];
#pragma unroll
        for (int j = 0; j < 4; ++j) {
            float x = s1v + sA[j];
            float p = (a0[j] > 0) ? __expf(fmaxf(x, 0.2f * x)) : 0.0f;
            pa[j] = p; dsum += p;
            float x2 = s1v + sB[j];
            float p2 = (a1[j] > 0) ? __expf(fmaxf(x2, 0.2f * x2)) : 0.0f;
            pb_[j] = p2; dsum += p2;
        }
        v4i pv;
        pv[0] = cvt_pk(pa[0], pa[1]);
        pv[1] = cvt_pk(pa[2], pa[3]);
        pv[2] = cvt_pk(pb_[0], pb_[1]);
        pv[3] = cvt_pk(pb_[2], pb_[3]);
        *(v4i*)&P_lds[0][woff] = pv;
    }
    __syncthreads();

    for (int s = 0; s < NSTEP; ++s) {
        // adj for step s+2
        int kn = (s < NSTEP - 2) ? (s + 2) * KSTEP : 0;
        v4i nx0 = __builtin_nontemporal_load((const v4i*)(arow + kn));
        v4i nx1 = __builtin_nontemporal_load((const v4i*)(arow + kn + 4));

        // B-frags for step s: one k-tile, cols g*64..g*64+63;
        // contiguous 1 KiB per wave-load, loaded ONCE, reused over 4 rowhalves
        s8v bf[4];
#pragma unroll
        for (int t = 0; t < 4; ++t)
            bf[t] = *(const s8v*)(pbb + (size_t)(s * 16 + g * 4 + t) * 512);

        // P for step s+1 from cur
        if (s < NSTEP - 1) {
            int kb = (s + 1) * KSTEP + idx * 8;
            v4f sA = *(const v4f*)&s2_lds[kb];
            v4f sB = *(const v4f*)&s2_lds[kb + 4];
            float pa[4], pb_[4];
#pragma unroll
            for (int j = 0; j < 4; ++j) {
                float x = s1v + sA[j];
                float p = (cur0[j] > 0) ? __expf(fmaxf(x, 0.2f * x)) : 0.0f;
                pa[j] = p; dsum += p;
                float x2 = s1v + sB[j];
                float p2 = (cur1[j] > 0) ? __expf(fmaxf(x2, 0.2f * x2)) : 0.0f;
                pb_[j] = p2; dsum += p2;
            }
            v4i pv;
            pv[0] = cvt_pk(pa[0], pa[1]);
            pv[1] = cvt_pk(pa[2], pa[3]);
            pv[2] = cvt_pk(pb_[0], pb_[1]);
            pv[3] = cvt_pk(pb_[2], pb_[3]);
            *(v4i*)&P_lds[(s + 1) & 1][woff] = pv;
        }

        // MFMA over 4 rowhalves; A-frag loaded per-rh to cap register pressure
        const unsigned short* pbuf = P_lds[s & 1];
#pragma unroll
        for (int rh = 0; rh < 4; ++rh) {
            s8v af = *(const s8v*)&pbuf[((q * 64 + rh * 16 + l15) * 8) ^ (q * 16)];
#pragma unroll
            for (int t = 0; t < 4; ++t)
                acc[rh][t] = __builtin_amdgcn_mfma_f32_16x16x32_bf16(af, bf[t], acc[rh][t], 0, 0, 0);
        }

        __syncthreads();
        cur0 = nx0; cur1 = nx1;
    }

    // partial denominator (fp32 p, no bf16 round-trip)
    dsum_lds[m][idx] = dsum;
    __syncthreads();
    if (tid < TROWS) {
        float d = dsum_lds[tid][0] + dsum_lds[tid][1] + dsum_lds[tid][2] + dsum_lds[tid][3];
        dpart[jc * NNODES + rt * TROWS + tid] = d;
    }

    // partial numerator: row = rh*16 + q*4 + r, col = g*64 + t*16 + l15
#pragma unroll
    for (int rh = 0; rh < 4; ++rh)
#pragma unroll
        for (int r = 0; r < 4; ++r) {
            int row = rh * 16 + q * 4 + r;
            float* base = Npart + ((size_t)(jc * NNODES) + rt * TROWS + row) * FDIM;
#pragma unroll
            for (int t = 0; t < 4; ++t)
                __builtin_nontemporal_store(acc[rh][t][r], base + g * 64 + t * 16 + l15);
        }
}

// ---------------- Kernel 3: reduce partials, normalize ----------------
__global__ __launch_bounds__(256) void reduce_kernel(
    const float* __restrict__ Npart, const float* __restrict__ dpart,
    float* __restrict__ out)
{
    int i = blockIdx.x, n = threadIdx.x;
    float d = 0.f, acc = 0.f;
#pragma unroll
    for (int jc = 0; jc < NJC; ++jc) {
        d += dpart[jc * NNODES + i];
        acc += Npart[((size_t)(jc * NNODES) + i) * FDIM + n];
    }
    out[(size_t)i * FDIM + n] = acc / fmaxf(d, 1e-30f);
}

extern "C" void kernel_launch(void* const* d_in, const int* in_sizes, int n_in,
                              void* d_out, int out_size, void* d_ws, size_t ws_size,
                              hipStream_t stream) {
    const float* h   = (const float*)d_in[0];
    const int*   adj = (const int*)d_in[1];
    const float* W   = (const float*)d_in[2];
    const float* a   = (const float*)d_in[3];
    float* out = (float*)d_out;

    char* ws = (char*)d_ws;
    unsigned short* PB = (unsigned short*)ws;                  // 4 MiB (tiled Wh)
    float* s1 = (float*)(ws + (4u << 20));                     // 32 KiB
    float* s2 = (float*)(ws + (4u << 20) + (32u << 10));       // 32 KiB
    unsigned short* WT = (unsigned short*)(ws + (4u << 20) + (64u << 10));   // 128 KiB
    float* v1 = (float*)(ws + (4u << 20) + (192u << 10));      // 1 KiB
    float* v2 = (float*)(ws + (4u << 20) + (193u << 10));      // 1 KiB
    float* dpart = (float*)(ws + (5u << 20));                  // 256 KiB
    float* Npart = (float*)(ws + (8u << 20));                  // 64 MiB

    hipLaunchKernelGGL(wt_kernel, dim3(256), dim3(256), 0, stream, W, WT);
    hipLaunchKernelGGL(wv_kernel, dim3(256), dim3(256), 0, stream, W, a, v1, v2);
    hipLaunchKernelGGL(wh_kernel, dim3(128), dim3(256), 0, stream, h, WT, v1, v2, PB, s1, s2);
    hipLaunchKernelGGL(attn_partial, dim3(128 * NJC), dim3(256), 0, stream,
                       adj, PB, s1, s2, Npart, dpart);
    hipLaunchKernelGGL(reduce_kernel, dim3(NNODES), dim3(256), 0, stream, Npart, dpart, out);
}

// Round 2
// 439.022 us; speedup vs baseline: 1.0632x; 1.0632x over previous
//
#include <hip/hip_runtime.h>

typedef short s8v  __attribute__((ext_vector_type(8)));
typedef float f4v  __attribute__((ext_vector_type(4)));
typedef int   v4i  __attribute__((ext_vector_type(4)));
typedef float v4f  __attribute__((ext_vector_type(4)));
typedef int   v2i  __attribute__((ext_vector_type(2)));

#define NNODES 8192
#define FDIM   256
#define NJC    4          // j-chunks (split-K factor) (R11: back to 4; 8 spilled + doubled Npart)
#define JLEN   2048       // columns-j per chunk
#define TROWS  64         // rows per block (B-frag reg reuse x4)
#define KSTEP  32         // k per step = one PB k-tile
#define NSTEP  64         // JLEN / KSTEP

__device__ __forceinline__ float bf2f(unsigned short u) {
    unsigned int x = ((unsigned int)u) << 16;
    return __builtin_bit_cast(float, x);
}
__device__ __forceinline__ unsigned short f2bf(float f) {
    unsigned int x = __builtin_bit_cast(unsigned int, f);
    x += 0x7fffu + ((x >> 16) & 1u);
    return (unsigned short)(x >> 16);
}
// RTNE pack of 2 f32 -> 1 dword of 2 bf16
__device__ __forceinline__ int cvt_pk(float lo, float hi) {
    int r;
    asm("v_cvt_pk_bf16_f32 %0, %1, %2" : "=v"(r) : "v"(lo), "v"(hi));
    return r;
}

// Barrier WITHOUT vmcnt drain (R11: __syncthreads emits s_waitcnt vmcnt(0)
// lgkmcnt(0) before s_barrier, killing the 2-step adj prefetch every step.
// LDS visibility needs only lgkmcnt(0); vmem data-deps are compiler-waited.)
// The trailing empty asm stops LDS reads from hoisting above the barrier.
__device__ __forceinline__ void barrier_lds_only() {
    asm volatile("s_waitcnt lgkmcnt(0)" ::: "memory");
    __builtin_amdgcn_s_barrier();
    asm volatile("" ::: "memory");
}

// ---------------- Kernel 0: fused WT + wv ----------------
// blocks 0..255:  WT[n][k] = bf16(W[k][n])
// blocks 256..511: v1[b]=W[b,:]@a[:256], v2[b]=W[b,:]@a[256:]
__global__ __launch_bounds__(256) void prep_kernel(const float* __restrict__ W,
                                                   const float* __restrict__ a,
                                                   unsigned short* __restrict__ WT,
                                                   float* __restrict__ v1,
                                                   float* __restrict__ v2) {
    if (blockIdx.x < 256) {
        int idx = blockIdx.x * 256 + threadIdx.x;
        int r = idx >> 8, c = idx & 255;
        WT[c * 256 + r] = f2bf(W[r * 256 + c]);
    } else {
        __shared__ float r1[256], r2[256];
        int b = blockIdx.x - 256, n = threadIdx.x;
        float w = W[(size_t)b * FDIM + n];
        r1[n] = w * a[n];
        r2[n] = w * a[FDIM + n];
        __syncthreads();
        for (int off = 128; off > 0; off >>= 1) {
            if (n < off) { r1[n] += r1[n + off]; r2[n] += r2[n + off]; }
            __syncthreads();
        }
        if (n == 0) { v1[b] = r1[0]; v2[b] = r2[0]; }
    }
}

// ---------------- Kernel 1: PB = tiled bf16 Wh; s1/s2 = h@v (fp32) ----------------
// PB: for k-block kb (32 Wh-rows) and n-block t (16 cols), 1 KiB tile:
//   PB[(kb*16+t)*512 + l15*32 + q*8 + jj] = Wh[kb*32 + q*8 + jj][t*16 + l15]
__global__ __launch_bounds__(256) void wh_kernel(
    const float* __restrict__ h, const unsigned short* __restrict__ WT,
    const float* __restrict__ v1, const float* __restrict__ v2,
    unsigned short* __restrict__ PB,
    float* __restrict__ s1, float* __restrict__ s2)
{
    __shared__ float v1_lds[FDIM], v2_lds[FDIM];
    int tid = threadIdx.x;
    v1_lds[tid] = v1[tid];
    v2_lds[tid] = v2[tid];
    __syncthreads();

    int w = tid >> 6, lane = tid & 63, q = lane >> 4, l15 = lane & 15;
    int i_base = blockIdx.x * 64 + w * 16;

    f4v acc[16] = {};
    float s1p = 0.f, s2p = 0.f;

    for (int k0 = 0; k0 < 256; k0 += 32) {
        const float* hp = h + (size_t)(i_base + l15) * FDIM + k0 + q * 8;
        f4v h0 = *(const f4v*)hp;
        f4v h1 = *(const f4v*)(hp + 4);
        union { v4i u; s8v s; } af;
        af.u[0] = cvt_pk(h0[0], h0[1]);
        af.u[1] = cvt_pk(h0[2], h0[3]);
        af.u[2] = cvt_pk(h1[0], h1[1]);
        af.u[3] = cvt_pk(h1[2], h1[3]);
#pragma unroll
        for (int j = 0; j < 4; ++j) {
            s1p += h0[j] * v1_lds[k0 + q * 8 + j] + h1[j] * v1_lds[k0 + q * 8 + 4 + j];
            s2p += h0[j] * v2_lds[k0 + q * 8 + j] + h1[j] * v2_lds[k0 + q * 8 + 4 + j];
        }
#pragma unroll
        for (int t = 0; t < 16; ++t) {
            s8v bf = *(const s8v*)(WT + (size_t)(t * 16 + l15) * FDIM + k0 + q * 8);
            acc[t] = __builtin_amdgcn_mfma_f32_16x16x32_bf16(af.s, bf, acc[t], 0, 0, 0);
        }
    }

    s1p += __shfl_xor(s1p, 16, 64);
    s1p += __shfl_xor(s1p, 32, 64);
    s2p += __shfl_xor(s2p, 16, 64);
    s2p += __shfl_xor(s2p, 32, 64);
    if (lane < 16) {
        s1[i_base + lane] = s1p;
        s2[i_base + lane] = s2p;
    }

    // packed epilogue: r=0..3 are 4 consecutive shorts at fixed (t,q)
#pragma unroll
    for (int t = 0; t < 16; ++t) {
        int i0 = i_base + q * 4;
        size_t a16 = (size_t)((i0 >> 5) * 16 + t) * 512
                   + l15 * 32 + ((i0 >> 3) & 3) * 8 + (i0 & 7);
        v2i pk;
        pk[0] = cvt_pk(acc[t][0], acc[t][1]);
        pk[1] = cvt_pk(acc[t][2], acc[t][3]);
        *(v2i*)(PB + a16) = pk;
    }
}

// ---------------- Kernel 2: split-K partial attention ----------------
// grid 512 = 128 row-tiles x 4 j-chunks, 256 threads. Block: 64 rows x 256
// cols, 64 steps of k=32. In-loop barriers are lgkmcnt-only so the 2-step
// adj prefetch and B-frag loads stay in flight across steps (T4 mechanism).
__global__ __launch_bounds__(256, 3) void attn_partial(
    const int* __restrict__ adj, const unsigned short* __restrict__ PB,
    const float* __restrict__ s1, const float* __restrict__ s2,
    float* __restrict__ Npart, float* __restrict__ dpart)
{
    __shared__ float s2_lds[JLEN];                      // 8 KB
    __shared__ unsigned short P_lds[2][TROWS * KSTEP];  // 2 x 4 KB
    __shared__ float dsum_lds[TROWS][4];

    int tid = threadIdx.x;
    int rt = blockIdx.x & 127, jc = blockIdx.x >> 7;
    int j0 = jc * JLEN;

    for (int i = tid; i < JLEN / 4; i += 256)
        ((v4f*)s2_lds)[i] = ((const v4f*)(s2 + j0))[i];

    // P-generator role: (row m 0..63, k-slice idx 0..3), 8 j's per thread/step
    int m = tid >> 2, idx = tid & 3;
    int row_g = rt * TROWS + m;
    float s1v = s1[row_g];
    const int* arow = adj + (size_t)row_g * NNODES + j0 + idx * 8;
    // write slot = idx*64+m, elem addr ^ idx*16 (matches reader swizzle)
    int woff = ((idx * 64 + m) * 8) ^ (idx * 16);

    // MFMA role: wave g -> cols g*64 + t*16 + l15; rowhalves rh=0..3 in-register
    int g = tid >> 6, lane = tid & 63, q = lane >> 4, l15 = lane & 15;
    const unsigned short* pbb = PB + (size_t)(jc * 64) * 16 * 512 + l15 * 32 + q * 8;

    f4v acc[4][4] = {};
    float dsum = 0.0f;

    __syncthreads();  // s2 staged (once; full drain fine here)

    // prologue: adj(step0) -> P0; adj(step1) parked in cur
    v4i a0 = __builtin_nontemporal_load((const v4i*)(arow));
    v4i a1 = __builtin_nontemporal_load((const v4i*)(arow + 4));
    v4i cur0 = __builtin_nontemporal_load((const v4i*)(arow + KSTEP));
    v4i cur1 = __builtin_nontemporal_load((const v4i*)(arow + KSTEP + 4));
    {
        int kb = idx * 8;
        v4f sA = *(const v4f*)&s2_lds[kb];
        v4f sB = *(const v4f*)&s2_lds[kb + 4];
        float pa[4], pb_[4];
#pragma unroll
        for (int j = 0; j < 4; ++j) {
            float x = s1v + sA[j];
            float p = (a0[j] > 0) ? __expf(fmaxf(x, 0.2f * x)) : 0.0f;
            pa[j] = p; dsum += p;
            float x2 = s1v + sB[j];
            float p2 = (a1[j] > 0) ? __expf(fmaxf(x2, 0.2f * x2)) : 0.0f;
            pb_[j] = p2; dsum += p2;
        }
        v4i pv;
        pv[0] = cvt_pk(pa[0], pa[1]);
        pv[1] = cvt_pk(pa[2], pa[3]);
        pv[2] = cvt_pk(pb_[0], pb_[1]);
        pv[3] = cvt_pk(pb_[2], pb_[3]);
        *(v4i*)&P_lds[0][woff] = pv;
    }
    barrier_lds_only();

    for (int s = 0; s < NSTEP; ++s) {
        // adj for step s+2 (stays in flight across the lgkm-only barrier)
        int kn = (s < NSTEP - 2) ? (s + 2) * KSTEP : 0;
        v4i nx0 = __builtin_nontemporal_load((const v4i*)(arow + kn));
        v4i nx1 = __builtin_nontemporal_load((const v4i*)(arow + kn + 4));

        // B-frags for step s: one k-tile, cols g*64..g*64+63;
        // contiguous 1 KiB per wave-load, loaded ONCE, reused over 4 rowhalves
        s8v bf[4];
#pragma unroll
        for (int t = 0; t < 4; ++t)
            bf[t] = *(const s8v*)(pbb + (size_t)(s * 16 + g * 4 + t) * 512);

        // P for step s+1 from cur
        if (s < NSTEP - 1) {
            int kb = (s + 1) * KSTEP + idx * 8;
            v4f sA = *(const v4f*)&s2_lds[kb];
            v4f sB = *(const v4f*)&s2_lds[kb + 4];
            float pa[4], pb_[4];
#pragma unroll
            for (int j = 0; j < 4; ++j) {
                float x = s1v + sA[j];
                float p = (cur0[j] > 0) ? __expf(fmaxf(x, 0.2f * x)) : 0.0f;
                pa[j] = p; dsum += p;
                float x2 = s1v + sB[j];
                float p2 = (cur1[j] > 0) ? __expf(fmaxf(x2, 0.2f * x2)) : 0.0f;
                pb_[j] = p2; dsum += p2;
            }
            v4i pv;
            pv[0] = cvt_pk(pa[0], pa[1]);
            pv[1] = cvt_pk(pa[2], pa[3]);
            pv[2] = cvt_pk(pb_[0], pb_[1]);
            pv[3] = cvt_pk(pb_[2], pb_[3]);
            *(v4i*)&P_lds[(s + 1) & 1][woff] = pv;
        }

        // MFMA over 4 rowhalves; A-frag loaded per-rh to cap register pressure
        const unsigned short* pbuf = P_lds[s & 1];
#pragma unroll
        for (int rh = 0; rh < 4; ++rh) {
            s8v af = *(const s8v*)&pbuf[((q * 64 + rh * 16 + l15) * 8) ^ (q * 16)];
#pragma unroll
            for (int t = 0; t < 4; ++t)
                acc[rh][t] = __builtin_amdgcn_mfma_f32_16x16x32_bf16(af, bf[t], acc[rh][t], 0, 0, 0);
        }

        barrier_lds_only();
        cur0 = nx0; cur1 = nx1;
    }

    // partial denominator
    dsum_lds[m][idx] = dsum;
    __syncthreads();
    if (tid < TROWS) {
        float d = dsum_lds[tid][0] + dsum_lds[tid][1] + dsum_lds[tid][2] + dsum_lds[tid][3];
        dpart[jc * NNODES + rt * TROWS + tid] = d;
    }

    // partial numerator: row = rh*16 + q*4 + r, col = g*64 + t*16 + l15
#pragma unroll
    for (int rh = 0; rh < 4; ++rh)
#pragma unroll
        for (int r = 0; r < 4; ++r) {
            int row = rh * 16 + q * 4 + r;
            float* base = Npart + ((size_t)(jc * NNODES) + rt * TROWS + row) * FDIM;
#pragma unroll
            for (int t = 0; t < 4; ++t)
                __builtin_nontemporal_store(acc[rh][t][r], base + g * 64 + t * 16 + l15);
        }
}

// ---------------- Kernel 3: reduce partials, normalize ----------------
__global__ __launch_bounds__(256) void reduce_kernel(
    const float* __restrict__ Npart, const float* __restrict__ dpart,
    float* __restrict__ out)
{
    int i = blockIdx.x, n = threadIdx.x;
    float d = 0.f, acc = 0.f;
#pragma unroll
    for (int jc = 0; jc < NJC; ++jc) {
        d += dpart[jc * NNODES + i];
        acc += Npart[((size_t)(jc * NNODES) + i) * FDIM + n];
    }
    out[(size_t)i * FDIM + n] = acc / fmaxf(d, 1e-30f);
}

extern "C" void kernel_launch(void* const* d_in, const int* in_sizes, int n_in,
                              void* d_out, int out_size, void* d_ws, size_t ws_size,
                              hipStream_t stream) {
    const float* h   = (const float*)d_in[0];
    const int*   adj = (const int*)d_in[1];
    const float* W   = (const float*)d_in[2];
    const float* a   = (const float*)d_in[3];
    float* out = (float*)d_out;

    char* ws = (char*)d_ws;
    unsigned short* PB = (unsigned short*)ws;                  // 4 MiB (tiled Wh)
    float* s1 = (float*)(ws + (4u << 20));                     // 32 KiB
    float* s2 = (float*)(ws + (4u << 20) + (32u << 10));       // 32 KiB
    unsigned short* WT = (unsigned short*)(ws + (4u << 20) + (64u << 10));   // 128 KiB
    float* v1 = (float*)(ws + (4u << 20) + (192u << 10));      // 1 KiB
    float* v2 = (float*)(ws + (4u << 20) + (193u << 10));      // 1 KiB
    float* dpart = (float*)(ws + (5u << 20));                  // 128 KiB
    float* Npart = (float*)(ws + (8u << 20));                  // 32 MiB

    hipLaunchKernelGGL(prep_kernel, dim3(512), dim3(256), 0, stream, W, a, WT, v1, v2);
    hipLaunchKernelGGL(wh_kernel, dim3(128), dim3(256), 0, stream, h, WT, v1, v2, PB, s1, s2);
    hipLaunchKernelGGL(attn_partial, dim3(128 * NJC), dim3(256), 0, stream,
                       adj, PB, s1, s2, Npart, dpart);
    hipLaunchKernelGGL(reduce_kernel, dim3(NNODES), dim3(256), 0, stream, Npart, dpart, out);
}